// Round 7
// baseline (166.003 us; speedup 1.0000x reference)
//
#include <hip/hip_runtime.h>
#include <hip/hip_bf16.h>
#include <math.h>

// Problem constants
#define LQ 196      // spatial tokens (14x14)
#define NH 12       // heads
#define DH 64       // head dim
#define CC 768      // output channels
#define NPAIR 28    // 4 n * 7 t' pairs per half
#define PQ ((size_t)LQ * LQ)   // 38416
#define NW 729      // (2*14-1)^2 w rows

#define KROWS2 224  // 14*16 (k padded so both k-halves run 7 uniform tiles)
#define LPITCH 72   // shorts per Ks LDS row (64 + 8 pad)
#define APITCH 232  // out-kernel A LDS pitch

// ws layout (in shorts):
//   Pm  [0, 2151296)          : head-mean attention, 2*28 planes x PQ bf16 (4.3 MB)
//   Wb  [+1119744)            : W1|W2 bf16
//   Qb  [+4816896)            : Q bf16, layout [nt][h][l<196][64]
//   Kb  [+4816896)            : K bf16, same layout
#define PM_SHORTS ((size_t)2 * NPAIR * PQ)
#define WB_OFF    PM_SHORTS
#define WB_SHORTS ((size_t)2 * NW * CC)
#define QB_OFF    (WB_OFF + WB_SHORTS)
#define QB_SHORTS ((size_t)32 * NH * LQ * DH)
#define KB_OFF    (QB_OFF + QB_SHORTS)

typedef short short8 __attribute__((ext_vector_type(8)));
typedef float f32x4  __attribute__((ext_vector_type(4)));

__device__ __forceinline__ short f2bf(float f) {
    __hip_bfloat16 h = __float2bfloat16(f);
    return __builtin_bit_cast(short, h);
}

// ---------------------------------------------------------------------------
// PREP (one launch): zero Out l=0 rows | W1,W2 -> bf16 | Q,K -> bf16 head-major
#define ZBLK 96
#define WBLK 1094                    // ceil(2*NW*CC/4 / 256)
#define QKBLK 9408                   // 2*32*12*196*16 / 256
__global__ __launch_bounds__(256) void prep_kernel(
    const float* __restrict__ Q, const float* __restrict__ K,
    const float* __restrict__ W1, const float* __restrict__ W2,
    short* __restrict__ Wb, short* __restrict__ Qb, short* __restrict__ Kb,
    float* __restrict__ Out)
{
    int b = blockIdx.x, tid = threadIdx.x;
    if (b < ZBLK) {
        int e = b * 256 + tid;                        // < 24576
        int nt = e / CC, c = e % CC;
        Out[(size_t)nt * 197 * CC + c] = 0.f;
    } else if (b < ZBLK + WBLK) {
        int e4 = (b - ZBLK) * 256 + tid;
        const int N4 = NW * CC / 4;                   // 139968
        if (e4 < 2 * N4) {
            const float* src = (e4 < N4) ? (W1 + (size_t)e4 * 4)
                                         : (W2 + (size_t)(e4 - N4) * 4);
            float4 f = *(const float4*)src;
            short4 v = {f2bf(f.x), f2bf(f.y), f2bf(f.z), f2bf(f.w)};
            *(short4*)(Wb + (size_t)e4 * 4) = v;
        }
    } else {
        int e4 = (b - ZBLK - WBLK) * 256 + tid;       // < 2408448
        const int HALF4 = 1204224;                    // 32*12*196*16
        int loc = (e4 < HALF4) ? e4 : e4 - HALF4;
        int c4 = loc & 15;
        int r1 = loc >> 4;
        int l  = r1 % LQ;
        int r2 = r1 / LQ;
        int h  = r2 % NH;
        int nt = r2 / NH;
        const float* base = (e4 < HALF4) ? Q : K;
        short* dst = ((e4 < HALF4) ? Qb : Kb) + (size_t)loc * 4;
        const float* s = base + (size_t)((nt * 197 + 1 + l) * NH + h) * DH + c4 * 4;
        float4 f = *(const float4*)s;
        short4 v = {f2bf(f.x), f2bf(f.y), f2bf(f.z), f2bf(f.w)};
        *(short4*)dst = v;
    }
}

// ---------------------------------------------------------------------------
// ATTN fused over heads: per (hf, pair, 32-row q-group):
//   Pm[plane][q][k] = mean_h softmax_k(Q_h . K_h / 8)
// 4 waves: wave = (strip in {0,1}) x (khalf in {0,1}); each wave owns
// 16 q-rows x 112 k-cols (7 MFMA tiles, K padded to 224 rows).
// Per head: linear-copy K head-slice to LDS; 14 mfma_f32_16x16x32_bf16;
// exp; 2-wave row-sum exchange via LDS; pm += exp/(12*l) in fp32 regs.
// Epilogue: pm -> LDS strip -> linear b128 stores (R5 lesson: C-order scalar
// stores = 16x transaction inflation).
__global__ __launch_bounds__(256) void attn_fused_kernel(
    const short* __restrict__ Qb, const short* __restrict__ Kb,
    short* __restrict__ Pm)
{
    int bid = blockIdx.x;
    int qg = bid % 7;
    int p  = (bid / 7) % NPAIR;      // pair = n*7 + i
    int hf = bid / (7 * NPAIR);      // 0: (q[t+1],k[t])  1: (q[t],k[t+1])
    int n = p / 7, i = p % 7;
    int tq = hf ? i     : i + 1;
    int tk = hf ? i + 1 : i;

    __shared__ __align__(16) short Ks[KROWS2 * LPITCH];   // 32.3 KB
    __shared__ __align__(16) short Ps[32 * LQ];           // 12.25 KB
    __shared__ float red[2][2][16];                       // [strip][khalf][row]

    int tid  = threadIdx.x;
    int wave = tid >> 6, lane = tid & 63;
    int m16  = lane & 15, q4 = lane >> 4;
    int strip = wave >> 1, khalf = wave & 1;
    int tb = khalf * 7;              // this wave's tile base (k-cols tb*16..)

    const short* Qh = Qb + (size_t)((n * 8 + tq) * NH) * (LQ * DH);
    const short* Kh = Kb + (size_t)((n * 8 + tk) * NH) * (LQ * DH);

    int qrow = qg * 32 + strip * 16 + m16;
    int qr = (qrow < LQ) ? qrow : (LQ - 1);   // clamp; rows >=196 never stored

    f32x4 pm[7];
#pragma unroll
    for (int t = 0; t < 7; ++t) pm[t] = (f32x4){0.f, 0.f, 0.f, 0.f};

    for (int h = 0; h < NH; ++h) {
        // stage K head-slice: pure linear b128 copy (rows >=196 zeroed)
        const short* ksrc = Kh + (size_t)h * (LQ * DH);
        for (int e = tid; e < KROWS2 * 8; e += 256) {
            int r = e >> 3, c8 = e & 7;
            short8 v = {0, 0, 0, 0, 0, 0, 0, 0};
            if (r < LQ) v = *(const short8*)(ksrc + r * 64 + c8 * 8);
            *(short8*)&Ks[r * LPITCH + c8 * 8] = v;
        }
        __syncthreads();

        // A-fragments straight from global (bf16, contiguous 16 B)
        const short* qp = Qh + (size_t)h * (LQ * DH) + (size_t)qr * 64 + q4 * 8;
        short8 a0 = *(const short8*)(qp);
        short8 a1 = *(const short8*)(qp + 32);

        f32x4 acc[7];
#pragma unroll
        for (int t = 0; t < 7; ++t) acc[t] = (f32x4){0.f, 0.f, 0.f, 0.f};
#pragma unroll
        for (int t = 0; t < 7; ++t) {
            const short* kp = &Ks[((tb + t) * 16 + m16) * LPITCH + q4 * 8];
            short8 b0 = *(const short8*)(kp);
            short8 b1 = *(const short8*)(kp + 32);
            acc[t] = __builtin_amdgcn_mfma_f32_16x16x32_bf16(a0, b0, acc[t], 0, 0, 0);
            acc[t] = __builtin_amdgcn_mfma_f32_16x16x32_bf16(a1, b1, acc[t], 0, 0, 0);
        }

        // exp (no max-sub: logits ~N(0,1)) + this wave's partial row sums
        float v4[4] = {0.f, 0.f, 0.f, 0.f};
#pragma unroll
        for (int t = 0; t < 7; ++t) {
            int k = (tb + t) * 16 + m16;
#pragma unroll
            for (int r = 0; r < 4; ++r) {
                float pe = (k < LQ) ? __expf(acc[t][r] * 0.125f) : 0.f;
                acc[t][r] = pe;
                v4[r] += pe;
            }
        }
#pragma unroll
        for (int r = 0; r < 4; ++r) {
            v4[r] += __shfl_xor(v4[r], 1, 64);
            v4[r] += __shfl_xor(v4[r], 2, 64);
            v4[r] += __shfl_xor(v4[r], 4, 64);
            v4[r] += __shfl_xor(v4[r], 8, 64);
        }
        if (m16 == 0) {
#pragma unroll
            for (int r = 0; r < 4; ++r) red[strip][khalf][q4 * 4 + r] = v4[r];
        }
        __syncthreads();

        float inv[4];
#pragma unroll
        for (int r = 0; r < 4; ++r)
            inv[r] = 1.0f / (12.0f * (red[strip][0][q4 * 4 + r] +
                                      red[strip][1][q4 * 4 + r]));
#pragma unroll
        for (int t = 0; t < 7; ++t)
#pragma unroll
            for (int r = 0; r < 4; ++r) pm[t][r] += acc[t][r] * inv[r];
        // next head's staging may start immediately: it only writes Ks, and all
        // Ks reads (MFMA) finished before the red barrier above.
    }

    // epilogue: pm -> Ps strip -> linear coalesced stores
#pragma unroll
    for (int t = 0; t < 7; ++t) {
        int k = (tb + t) * 16 + m16;
        if (k < LQ) {
#pragma unroll
            for (int r = 0; r < 4; ++r)
                Ps[(strip * 16 + q4 * 4 + r) * LQ + k] = f2bf(pm[t][r]);
        }
    }
    __syncthreads();

    int plane = hf * NPAIR + p;
    int row0 = qg * 32;
    int rows = LQ - row0; if (rows > 32) rows = 32;    // qg=6 -> 4 rows
    int nb = rows * (LQ * 2);                          // bytes, mult of 16
    char* dst = (char*)(Pm + (size_t)plane * PQ + (size_t)row0 * LQ);
    const char* sp = (const char*)Ps;
    for (int e = tid * 16; e < nb; e += 256 * 16)
        *(short8*)(dst + e) = *(const short8*)(sp + e);
}

// ---------------------------------------------------------------------------
// OUT (MFMA): per q: Out[n*8+t][c] = sum_k A1[n*7+t-1][q][k]*W1[idx(q,k)][c]
//                                  + sum_k A2[n*7+t  ][q][k]*W2[idx(q,k)][c]
// T-shifted A staging (M=32, one acc set); B gathered from bf16 Wb via
// premultiplied LDS idx table. grid (196, 2): y = c-half. Reads Pm directly.
__global__ __launch_bounds__(256) void out_mfma_kernel(
    const short* __restrict__ Pm, const short* __restrict__ Wb,
    float* __restrict__ Out)
{
    int q   = blockIdx.x;
    int yb  = blockIdx.y;
    int tid = threadIdx.x;
    int wave = tid >> 6, lane = tid & 63;
    int n16 = lane & 15, q4 = lane >> 4;

    __shared__ __align__(16) short A1s[32 * APITCH];   // 14.8 KB
    __shared__ __align__(16) short A2s[32 * APITCH];
    __shared__ int idxs[224];                          // premultiplied by CC

    const short* Wb1 = Wb;
    const short* Wb2 = Wb + (size_t)NW * CC;

    int pi = q / 14, pj = q % 14;
    for (int k = tid; k < 224; k += 256) {
        int v = 0;
        if (k < LQ) { int ki = k / 14, kj = k % 14; v = (pi - ki + 13) * 27 + (pj - kj + 13); }
        idxs[k] = v * CC;
    }

    // A staging: 64 rows x 58 short4 slots (APITCH=232)
    for (int e = tid; e < 64 * 58; e += 256) {
        int r2 = e / 58, c4 = e % 58;
        int k4 = c4 * 4;
        int r = r2 & 31, hfsel = r2 >> 5;      // 0 -> A1s, 1 -> A2s
        int n = r >> 3, t = r & 7;
        int pl = hfsel ? t : t - 1;
        short4 v = {0, 0, 0, 0};
        if (pl >= 0 && pl <= 6 && k4 < LQ) {
            const short* src = Pm + (size_t)(hfsel * NPAIR + n * 7 + pl) * PQ
                                  + (size_t)q * LQ + k4;
            v = *(const short4*)src;
        }
        *(short4*)((hfsel ? A2s : A1s) + r * APITCH + k4) = v;
    }
    __syncthreads();

    for (int i = 0; i < 6; ++i) {
        int nt = yb * 24 + wave * 6 + i;
        int c0 = nt * 16;
        int cn = c0 + n16;
        f32x4 acc0 = {0.f, 0.f, 0.f, 0.f}, acc1 = {0.f, 0.f, 0.f, 0.f};

        for (int ks = 0; ks < 7; ++ks) {
            int kb = ks * 32 + q4 * 8;
            short8 b1, b2;
#pragma unroll
            for (int j = 0; j < 8; ++j) {
                int o = idxs[kb + j];
                b1[j] = Wb1[o + cn];
                b2[j] = Wb2[o + cn];
            }

            short8 a10 = *(const short8*)&A1s[n16 * APITCH + kb];
            short8 a11 = *(const short8*)&A1s[(16 + n16) * APITCH + kb];
            short8 a20 = *(const short8*)&A2s[n16 * APITCH + kb];
            short8 a21 = *(const short8*)&A2s[(16 + n16) * APITCH + kb];
            acc0 = __builtin_amdgcn_mfma_f32_16x16x32_bf16(a10, b1, acc0, 0, 0, 0);
            acc0 = __builtin_amdgcn_mfma_f32_16x16x32_bf16(a20, b2, acc0, 0, 0, 0);
            acc1 = __builtin_amdgcn_mfma_f32_16x16x32_bf16(a11, b1, acc1, 0, 0, 0);
            acc1 = __builtin_amdgcn_mfma_f32_16x16x32_bf16(a21, b2, acc1, 0, 0, 0);
        }

#pragma unroll
        for (int mt = 0; mt < 2; ++mt) {
            f32x4 a = mt ? acc1 : acc0;
#pragma unroll
            for (int r = 0; r < 4; ++r) {
                int row = mt * 16 + q4 * 4 + r;     // = n*8 + t
                Out[(size_t)(row * 197 + 1 + q) * CC + cn] = a[r];
            }
        }
    }
}

// ---------------------------------------------------------------------------
extern "C" void kernel_launch(void* const* d_in, const int* in_sizes, int n_in,
                              void* d_out, int out_size, void* d_ws, size_t ws_size,
                              hipStream_t stream) {
    const float* Q  = (const float*)d_in[0];
    const float* K  = (const float*)d_in[1];
    const float* W1 = (const float*)d_in[2];
    const float* W2 = (const float*)d_in[3];
    float* Out = (float*)d_out;
    short* Pm = (short*)d_ws;                 // 4.3 MB
    short* Wb = (short*)d_ws + WB_OFF;        // 2.24 MB
    short* Qb = (short*)d_ws + QB_OFF;        // 9.63 MB
    short* Kb = (short*)d_ws + KB_OFF;        // 9.63 MB

    hipLaunchKernelGGL(prep_kernel, dim3(ZBLK + WBLK + QKBLK), dim3(256), 0, stream,
                       Q, K, W1, W2, Wb, Qb, Kb, Out);
    hipLaunchKernelGGL(attn_fused_kernel, dim3(2 * NPAIR * 7), dim3(256), 0, stream,
                       Qb, Kb, Pm);
    hipLaunchKernelGGL(out_mfma_kernel, dim3(196, 2), dim3(256), 0, stream,
                       Pm, Wb, Out);
}

// Round 8
// 148.098 us; speedup vs baseline: 1.1209x; 1.1209x over previous
//
#include <hip/hip_runtime.h>
#include <hip/hip_bf16.h>
#include <math.h>

// Problem constants
#define LQ 196      // spatial tokens (14x14)
#define NH 12       // heads
#define DH 64       // head dim
#define CC 768      // output channels
#define NPAIR 28    // 4 n * 7 t' pairs per half
#define PQ ((size_t)LQ * LQ)   // 38416
#define NW 729      // (2*14-1)^2 w rows

#define KROWS2 224  // 14*16 (k padded so both k-halves run 7 uniform tiles)
#define LPITCH 72   // shorts per Ks LDS row (64 + 8 pad)
#define APITCH 232  // out-kernel A LDS pitch

// ws layout (in shorts):
#define PM_SHORTS ((size_t)2 * NPAIR * PQ)
#define WB_OFF    PM_SHORTS
#define WB_SHORTS ((size_t)2 * NW * CC)
#define QB_OFF    (WB_OFF + WB_SHORTS)
#define QB_SHORTS ((size_t)32 * NH * LQ * DH)
#define KB_OFF    (QB_OFF + QB_SHORTS)

typedef short short8 __attribute__((ext_vector_type(8)));
typedef float f32x4  __attribute__((ext_vector_type(4)));

__device__ __forceinline__ short f2bf(float f) {
    __hip_bfloat16 h = __float2bfloat16(f);
    return __builtin_bit_cast(short, h);
}

// ---------------------------------------------------------------------------
// PREP (one launch): zero Out l=0 rows | W1,W2 -> bf16 | Q,K -> bf16 head-major
#define ZBLK 96
#define WBLK 1094                    // ceil(2*NW*CC/4 / 256)
#define QKBLK 9408                   // 2*32*12*196*16 / 256
__global__ __launch_bounds__(256) void prep_kernel(
    const float* __restrict__ Q, const float* __restrict__ K,
    const float* __restrict__ W1, const float* __restrict__ W2,
    short* __restrict__ Wb, short* __restrict__ Qb, short* __restrict__ Kb,
    float* __restrict__ Out)
{
    int b = blockIdx.x, tid = threadIdx.x;
    if (b < ZBLK) {
        int e = b * 256 + tid;                        // < 24576
        int nt = e / CC, c = e % CC;
        Out[(size_t)nt * 197 * CC + c] = 0.f;
    } else if (b < ZBLK + WBLK) {
        int e4 = (b - ZBLK) * 256 + tid;
        const int N4 = NW * CC / 4;                   // 139968
        if (e4 < 2 * N4) {
            const float* src = (e4 < N4) ? (W1 + (size_t)e4 * 4)
                                         : (W2 + (size_t)(e4 - N4) * 4);
            float4 f = *(const float4*)src;
            short4 v = {f2bf(f.x), f2bf(f.y), f2bf(f.z), f2bf(f.w)};
            *(short4*)(Wb + (size_t)e4 * 4) = v;
        }
    } else {
        int e4 = (b - ZBLK - WBLK) * 256 + tid;       // < 2408448
        const int HALF4 = 1204224;                    // 32*12*196*16
        int loc = (e4 < HALF4) ? e4 : e4 - HALF4;
        int c4 = loc & 15;
        int r1 = loc >> 4;
        int l  = r1 % LQ;
        int r2 = r1 / LQ;
        int h  = r2 % NH;
        int nt = r2 / NH;
        const float* base = (e4 < HALF4) ? Q : K;
        short* dst = ((e4 < HALF4) ? Qb : Kb) + (size_t)loc * 4;
        const float* s = base + (size_t)((nt * 197 + 1 + l) * NH + h) * DH + c4 * 4;
        float4 f = *(const float4*)s;
        short4 v = {f2bf(f.x), f2bf(f.y), f2bf(f.z), f2bf(f.w)};
        *(short4*)dst = v;
    }
}

// ---------------------------------------------------------------------------
// ATTN fused over heads, DOUBLE-BUFFERED (R7: 80% stall — per-head stage
// latency fully exposed). Per head h: issue K/Q prefetch for h+1 into VGPRs
// (K stage address is linear: src = k0 + 8*e), compute MFMA+softmax on
// Ks[cur], write prefetch into Ks[1-cur], ONE barrier. red[] double-buffered
// so the single barrier is race-free. XCD swizzle: all 7 q-group blocks of a
// plane share blockIdx%8 -> same XCD -> K hot-set ~2.1 MB fits 4 MB L2.
__global__ __launch_bounds__(256) void attn_fused_kernel(
    const short* __restrict__ Qb, const short* __restrict__ Kb,
    short* __restrict__ Pm)
{
    int bid  = blockIdx.x;
    int xcd  = bid & 7;
    int slot = bid >> 3;
    int plane = xcd + 8 * (slot / 7);    // 0..55 = hf*28 + p
    int qg    = slot % 7;
    int p  = plane % NPAIR;
    int hf = plane / NPAIR;              // 0: (q[t+1],k[t])  1: (q[t],k[t+1])
    int n = p / 7, i = p % 7;
    int tq = hf ? i     : i + 1;
    int tk = hf ? i + 1 : i;

    __shared__ __align__(16) short Ks[2][KROWS2 * LPITCH];  // 64.5 KB
    __shared__ __align__(16) short Ps[32 * LQ];             // 12.25 KB
    __shared__ float red[2][2][2][16];                      // [h&1][strip][khalf][row]

    int tid  = threadIdx.x;
    int wave = tid >> 6, lane = tid & 63;
    int m16  = lane & 15, q4 = lane >> 4;
    int strip = wave >> 1, khalf = wave & 1;
    int tb = khalf * 7;                  // wave's k-tile base

    const short* Qh = Qb + (size_t)((n * 8 + tq) * NH) * (LQ * DH);
    const short* Kh = Kb + (size_t)((n * 8 + tk) * NH) * (LQ * DH);

    int qrow = qg * 32 + strip * 16 + m16;
    int qr = (qrow < LQ) ? qrow : (LQ - 1);   // clamp; rows >=196 never stored
    const short* qbase = Qh + (size_t)qr * 64 + q4 * 8;

    // per-thread staging geometry: e = tid + 256*j; src is LINEAR (k0 + 8e)
    int sr[7], sw[7];  bool sv[7];
#pragma unroll
    for (int j = 0; j < 7; ++j) {
        int e = tid + 256 * j;
        int r = e >> 3, c8 = e & 7;
        sr[j] = 8 * e;                       // source offset (shorts)
        sw[j] = r * LPITCH + c8 * 8;         // LDS offset (shorts)
        sv[j] = (r < LQ);
    }

    // stage h=0
    {
        const short* k0 = Kh;
        short8 z = {0,0,0,0,0,0,0,0};
#pragma unroll
        for (int j = 0; j < 7; ++j) {
            short8 v = sv[j] ? *(const short8*)(k0 + sr[j]) : z;
            *(short8*)&Ks[0][sw[j]] = v;
        }
    }
    short8 qa0 = *(const short8*)(qbase);
    short8 qa1 = *(const short8*)(qbase + 32);
    __syncthreads();

    f32x4 pm[7];
#pragma unroll
    for (int t = 0; t < 7; ++t) pm[t] = (f32x4){0.f, 0.f, 0.f, 0.f};

    for (int h = 0; h < NH; ++h) {
        int cur = h & 1;

        // prefetch next head into VGPRs (overlaps compute below)
        short8 pfk[7], qn0, qn1;
        if (h < NH - 1) {
            const short* kn = Kh + (size_t)(h + 1) * (LQ * DH);
            short8 z = {0,0,0,0,0,0,0,0};
#pragma unroll
            for (int j = 0; j < 7; ++j)
                pfk[j] = sv[j] ? *(const short8*)(kn + sr[j]) : z;
            const short* qn = qbase + (size_t)(h + 1) * (LQ * DH);
            qn0 = *(const short8*)(qn);
            qn1 = *(const short8*)(qn + 32);
        }

        // MFMA on current buffer
        f32x4 acc[7];
#pragma unroll
        for (int t = 0; t < 7; ++t) acc[t] = (f32x4){0.f, 0.f, 0.f, 0.f};
#pragma unroll
        for (int t = 0; t < 7; ++t) {
            const short* kp = &Ks[cur][((tb + t) * 16 + m16) * LPITCH + q4 * 8];
            short8 b0 = *(const short8*)(kp);
            short8 b1 = *(const short8*)(kp + 32);
            acc[t] = __builtin_amdgcn_mfma_f32_16x16x32_bf16(qa0, b0, acc[t], 0, 0, 0);
            acc[t] = __builtin_amdgcn_mfma_f32_16x16x32_bf16(qa1, b1, acc[t], 0, 0, 0);
        }

        // exp (no max-sub: logits ~N(0,1)) + wave-partial row sums
        float v4[4] = {0.f, 0.f, 0.f, 0.f};
#pragma unroll
        for (int t = 0; t < 7; ++t) {
            int k = (tb + t) * 16 + m16;
#pragma unroll
            for (int r = 0; r < 4; ++r) {
                float pe = (k < LQ) ? __expf(acc[t][r] * 0.125f) : 0.f;
                acc[t][r] = pe;
                v4[r] += pe;
            }
        }
#pragma unroll
        for (int r = 0; r < 4; ++r) {
            v4[r] += __shfl_xor(v4[r], 1, 64);
            v4[r] += __shfl_xor(v4[r], 2, 64);
            v4[r] += __shfl_xor(v4[r], 4, 64);
            v4[r] += __shfl_xor(v4[r], 8, 64);
        }
        if (m16 == 0) {
#pragma unroll
            for (int r = 0; r < 4; ++r) red[cur][strip][khalf][q4 * 4 + r] = v4[r];
        }

        // commit prefetch into the other buffer (compiler inserts vmcnt wait)
        if (h < NH - 1) {
#pragma unroll
            for (int j = 0; j < 7; ++j) *(short8*)&Ks[1 - cur][sw[j]] = pfk[j];
        }
        __syncthreads();
        // safe: all Ks[cur] reads happened before this barrier; next head's
        // writes to Ks[cur] occur after it. red[cur] read below; next head
        // writes red[1-cur].

        float inv[4];
#pragma unroll
        for (int r = 0; r < 4; ++r)
            inv[r] = 1.0f / (12.0f * (red[cur][strip][0][q4 * 4 + r] +
                                      red[cur][strip][1][q4 * 4 + r]));
#pragma unroll
        for (int t = 0; t < 7; ++t)
#pragma unroll
            for (int r = 0; r < 4; ++r) pm[t][r] += acc[t][r] * inv[r];

        if (h < NH - 1) { qa0 = qn0; qa1 = qn1; }
    }

    // epilogue: pm -> Ps strip -> linear coalesced stores
#pragma unroll
    for (int t = 0; t < 7; ++t) {
        int k = (tb + t) * 16 + m16;
        if (k < LQ) {
#pragma unroll
            for (int r = 0; r < 4; ++r)
                Ps[(strip * 16 + q4 * 4 + r) * LQ + k] = f2bf(pm[t][r]);
        }
    }
    __syncthreads();

    int row0 = qg * 32;
    int rows = LQ - row0; if (rows > 32) rows = 32;    // qg=6 -> 4 rows
    int nb = rows * (LQ * 2);                          // bytes, mult of 16
    char* dst = (char*)(Pm + (size_t)plane * PQ + (size_t)row0 * LQ);
    const char* sp = (const char*)Ps;
    for (int e = tid * 16; e < nb; e += 256 * 16)
        *(short8*)(dst + e) = *(const short8*)(sp + e);
}

// ---------------------------------------------------------------------------
// OUT (MFMA): per q: Out[n*8+t][c] = sum_k A1[n*7+t-1][q][k]*W1[idx(q,k)][c]
//                                  + sum_k A2[n*7+t  ][q][k]*W2[idx(q,k)][c]
// T-shifted A staging (M=32, one acc set); B gathered from bf16 Wb via
// premultiplied LDS idx table. grid (196, 4): y = c-quarter (12 tiles of 16,
// 3 per wave) — doubles grid vs R7 to cut per-block serial latency.
__global__ __launch_bounds__(256) void out_mfma_kernel(
    const short* __restrict__ Pm, const short* __restrict__ Wb,
    float* __restrict__ Out)
{
    int q   = blockIdx.x;
    int yb  = blockIdx.y;
    int tid = threadIdx.x;
    int wave = tid >> 6, lane = tid & 63;
    int n16 = lane & 15, q4 = lane >> 4;

    __shared__ __align__(16) short A1s[32 * APITCH];   // 14.8 KB
    __shared__ __align__(16) short A2s[32 * APITCH];
    __shared__ int idxs[224];                          // premultiplied by CC

    const short* Wb1 = Wb;
    const short* Wb2 = Wb + (size_t)NW * CC;

    int pi = q / 14, pj = q % 14;
    for (int k = tid; k < 224; k += 256) {
        int v = 0;
        if (k < LQ) { int ki = k / 14, kj = k % 14; v = (pi - ki + 13) * 27 + (pj - kj + 13); }
        idxs[k] = v * CC;
    }

    // A staging: 64 rows x 58 short4 slots (APITCH=232)
    for (int e = tid; e < 64 * 58; e += 256) {
        int r2 = e / 58, c4 = e % 58;
        int k4 = c4 * 4;
        int r = r2 & 31, hfsel = r2 >> 5;      // 0 -> A1s, 1 -> A2s
        int n = r >> 3, t = r & 7;
        int pl = hfsel ? t : t - 1;
        short4 v = {0, 0, 0, 0};
        if (pl >= 0 && pl <= 6 && k4 < LQ) {
            const short* src = Pm + (size_t)(hfsel * NPAIR + n * 7 + pl) * PQ
                                  + (size_t)q * LQ + k4;
            v = *(const short4*)src;
        }
        *(short4*)((hfsel ? A2s : A1s) + r * APITCH + k4) = v;
    }
    __syncthreads();

    for (int i = 0; i < 3; ++i) {
        int nt = yb * 12 + wave * 3 + i;
        int c0 = nt * 16;
        int cn = c0 + n16;
        f32x4 acc0 = {0.f, 0.f, 0.f, 0.f}, acc1 = {0.f, 0.f, 0.f, 0.f};

        for (int ks = 0; ks < 7; ++ks) {
            int kb = ks * 32 + q4 * 8;
            short8 b1, b2;
#pragma unroll
            for (int j = 0; j < 8; ++j) {
                int o = idxs[kb + j];
                b1[j] = Wb1[o + cn];
                b2[j] = Wb2[o + cn];
            }

            short8 a10 = *(const short8*)&A1s[n16 * APITCH + kb];
            short8 a11 = *(const short8*)&A1s[(16 + n16) * APITCH + kb];
            short8 a20 = *(const short8*)&A2s[n16 * APITCH + kb];
            short8 a21 = *(const short8*)&A2s[(16 + n16) * APITCH + kb];
            acc0 = __builtin_amdgcn_mfma_f32_16x16x32_bf16(a10, b1, acc0, 0, 0, 0);
            acc0 = __builtin_amdgcn_mfma_f32_16x16x32_bf16(a20, b2, acc0, 0, 0, 0);
            acc1 = __builtin_amdgcn_mfma_f32_16x16x32_bf16(a11, b1, acc1, 0, 0, 0);
            acc1 = __builtin_amdgcn_mfma_f32_16x16x32_bf16(a21, b2, acc1, 0, 0, 0);
        }

#pragma unroll
        for (int mt = 0; mt < 2; ++mt) {
            f32x4 a = mt ? acc1 : acc0;
#pragma unroll
            for (int r = 0; r < 4; ++r) {
                int row = mt * 16 + q4 * 4 + r;     // = n*8 + t
                Out[(size_t)(row * 197 + 1 + q) * CC + cn] = a[r];
            }
        }
    }
}

// ---------------------------------------------------------------------------
extern "C" void kernel_launch(void* const* d_in, const int* in_sizes, int n_in,
                              void* d_out, int out_size, void* d_ws, size_t ws_size,
                              hipStream_t stream) {
    const float* Q  = (const float*)d_in[0];
    const float* K  = (const float*)d_in[1];
    const float* W1 = (const float*)d_in[2];
    const float* W2 = (const float*)d_in[3];
    float* Out = (float*)d_out;
    short* Pm = (short*)d_ws;                 // 4.3 MB
    short* Wb = (short*)d_ws + WB_OFF;        // 2.24 MB
    short* Qb = (short*)d_ws + QB_OFF;        // 9.63 MB
    short* Kb = (short*)d_ws + KB_OFF;        // 9.63 MB

    hipLaunchKernelGGL(prep_kernel, dim3(ZBLK + WBLK + QKBLK), dim3(256), 0, stream,
                       Q, K, W1, W2, Wb, Qb, Kb, Out);
    hipLaunchKernelGGL(attn_fused_kernel, dim3(2 * NPAIR * 7), dim3(256), 0, stream,
                       Qb, Kb, Pm);
    hipLaunchKernelGGL(out_mfma_kernel, dim3(196, 4), dim3(256), 0, stream,
                       Pm, Wb, Out);
}